// Round 17
// baseline (235.748 us; speedup 1.0000x reference)
//
#include <hip/hip_runtime.h>

// CavityModel forward: gaussian blur -> 3x(conv3d+maxpool+BN(batch stats)+leaky)
// -> dense 64->128 (+BN+leaky) -> 128->100 (+leaky) -> 100->20.
// R17: conv1 software pipeline: prefetch next tile's B-fragments (2nd register
// set) before the current tile's MFMA chain, hiding LDS latency under MFMA.
// All addressing/layout/staging frozen at R16 (proven). launch_bounds (256,4).

#define G2 324
#define G3 5832
#define NT 6
#define BATCH 256
#define APE 100
#define EPS 1e-5f

typedef unsigned short u16;
typedef unsigned int u32;
typedef _Float16 f16;
typedef _Float16 h2 __attribute__((ext_vector_type(2)));
typedef _Float16 f16x8 __attribute__((ext_vector_type(8)));
typedef float f32x4 __attribute__((ext_vector_type(4)));

__device__ __forceinline__ float leaky(float x) { return x >= 0.0f ? x : 0.01f * x; }
__device__ __forceinline__ u32 pkh(float a, float b) {
    h2 v; v[0] = (f16)a; v[1] = (f16)b;
    return __builtin_bit_cast(u32, v);
}

struct BF { f16x8 b[6]; };   // only ever indexed by unrolled compile-time c

// ---------- K1a: gaussian splat, separable outer product, NO atomics.
// block 0 zeroes the bn-stats buffer (runs strictly before all consumers).
__global__ __launch_bounds__(512) void k_splat(const float* __restrict__ pos,
        const int* __restrict__ types, u32* __restrict__ fields,
        float* __restrict__ stO) {
    __shared__ float ew[APE * 54];
    __shared__ float ssum[APE * 3];
    __shared__ int list[APE];
    __shared__ int base[NT + 1];
    __shared__ int cnt[NT], cur[NT];
    const int b = blockIdx.x, tid = threadIdx.x;

    if (b == 0 && tid < 480) stO[tid] = 0.0f;
    if (tid < NT) { cnt[tid] = 0; cur[tid] = 0; }
    __syncthreads();
    if (tid < APE) atomicAdd(&cnt[types[b * APE + tid]], 1);
    if (tid < 300) {
        const int la = tid / 3, ax = tid % 3;
        const float p = pos[(b * APE + la) * 3 + ax];
        float s = 0.0f;
        #pragma unroll
        for (int g = 0; g < 18; ++g) {
            const float d = (float)g - 8.5f - p;
            const float e = __expf(d * d * (-1.0f / 0.72f));
            ew[la * 54 + ax * 18 + g] = e;
            s += e;
        }
        ssum[tid] = s;
    }
    __syncthreads();
    if (tid == 0) {
        int s = 0;
        #pragma unroll
        for (int t = 0; t < NT; ++t) { base[t] = s; s += cnt[t]; }
        base[NT] = s;
    }
    if (tid < APE) {
        const float inv = 1.0f / (ssum[tid * 3] * ssum[tid * 3 + 1] * ssum[tid * 3 + 2]);
        #pragma unroll
        for (int g = 0; g < 18; ++g) ew[tid * 54 + g] *= inv;
    }
    __syncthreads();
    if (tid < APE) {
        const int t = types[b * APE + tid];
        const int j = atomicAdd(&cur[t], 1);
        list[base[t] + j] = tid;
    }
    __syncthreads();

    for (int it = tid; it < NT * 324; it += 512) {
        const int t = it / 324, r = it - t * 324;
        const int i = r / 18, j = r % 18;
        float acc[18];
        #pragma unroll
        for (int k = 0; k < 18; ++k) acc[k] = 0.0f;
        const int e1 = base[t + 1];
        for (int u = base[t]; u < e1; ++u) {
            const int a = list[u];
            const float exy = ew[a * 54 + i] * ew[a * 54 + 18 + j];
            const float* ez = &ew[a * 54 + 36];
            #pragma unroll
            for (int k = 0; k < 18; ++k) acc[k] += exy * ez[k];
        }
        u32* dst = &fields[((size_t)b * NT + t) * 2916 + (size_t)r * 9];
        #pragma unroll
        for (int q = 0; q < 9; ++q) dst[q] = pkh(acc[2 * q], acc[2 * q + 1]);
    }
}

// ---------- K1b: conv1 via MFMA implicit GEMM + 2x2x2 pool + bias + bn1 stats
// block = (env b, x-pair Xg 0..8); input tile fldP[ic 6][plane 4][y 20][z 20]
// f16 zero-padded; A = W[16 oc][192 k] in regs; per-plane MFMA with in-place
// x-max into outB[16][324]; B-fragments software-pipelined one tile ahead.
__global__ __launch_bounds__(256, 4) void k_conv1(const u32* __restrict__ fields,
        const float* __restrict__ w, const float* __restrict__ bias,
        float* __restrict__ a1, float* __restrict__ stO) {
    __shared__ f16 fldP[9600];     // 19200 B
    __shared__ f16 outB[16 * 324]; // 10368 B
    __shared__ u16 koffT[192];
    __shared__ float bs[16], s_sum[16], s_ssq[16];
    const int bx = blockIdx.x, b = bx / 9, Xg = bx % 9, tid = threadIdx.x;

    for (int i = tid; i < 4800; i += 256) ((u32*)fldP)[i] = 0u;
    if (tid < 192) {
        u16 off = 0;
        if (tid < 162) {
            const int ic = tid / 27, d = tid % 27;
            off = (u16)(ic * 1600 + (d / 9) * 400 + ((d / 3) % 3) * 20 + (d % 3));
        }
        koffT[tid] = off;
    }
    if (tid < 16) { bs[tid] = bias[tid]; s_sum[tid] = 0.0f; s_ssq[tid] = 0.0f; }

    const int lane = tid & 63, g = lane >> 4, m = lane & 15, wv = tid >> 6;
    f16x8 af[6];
    #pragma unroll
    for (int c = 0; c < 6; ++c)
        #pragma unroll
        for (int j = 0; j < 8; ++j) {
            const int k = 32 * c + 8 * g + j;
            af[c][j] = (k < 162) ? (f16)w[m * 162 + k] : (f16)0.0f;
        }
    __syncthreads();

    // stage interior: planes ix = 2Xg-1 .. 2Xg+2 (pads stay zero)
    for (int i = tid; i < 3888; i += 256) {
        const int p = i % 9, r2 = i / 9, iy = r2 % 18, r3 = r2 / 18;
        const int pl = r3 & 3, ic = r3 >> 2;
        const int ix = 2 * Xg - 1 + pl;
        if (ix >= 0 && ix < 18) {
            const u32 v = fields[((size_t)(b * 6 + ic) * 324 + ix * 18 + iy) * 9 + p];
            const h2 hv = __builtin_bit_cast(h2, v);
            const int e = ic * 1600 + pl * 400 + (iy + 1) * 20 + (2 * p + 1);
            fldP[e] = hv[0];
            fldP[e + 1] = hv[1];
        }
    }
    __syncthreads();

    u16 koffR[48];
    #pragma unroll
    for (int c = 0; c < 6; ++c)
        #pragma unroll
        for (int j = 0; j < 8; ++j)
            koffR[c * 8 + j] = koffT[32 * c + 8 * g + j];

    // per-wave virtual tile sequence: i in [0, 2*nj); plane = i >= nj,
    // t = wv + 4*(i - plane*nj); s = 16t + m.
    const int nj = (21 - wv + 3) / 4;
    const int nvt = 2 * nj;

    int p01c, sc_;
    int cbc;
    {
        p01c = 0;
        const int t0 = wv;
        sc_ = 16 * t0 + m;
        const int sv = (sc_ < 324) ? sc_ : 323;
        cbc = (sv / 18) * 20 + (sv % 18);
    }
    BF curB;
    #pragma unroll
    for (int c = 0; c < 6; ++c)
        #pragma unroll
        for (int j = 0; j < 8; ++j)
            curB.b[c][j] = fldP[cbc + (int)koffR[c * 8 + j]];

    for (int i = 0; i < nvt; ++i) {
        BF nxtB;
        int p01n = 0, sn = 0;
        if (i + 1 < nvt) {
            p01n = (i + 1 >= nj) ? 1 : 0;
            const int tn = wv + 4 * (i + 1 - p01n * nj);
            sn = 16 * tn + m;
            const int sv = (sn < 324) ? sn : 323;
            const int cbn = p01n * 400 + (sv / 18) * 20 + (sv % 18);
            #pragma unroll
            for (int c = 0; c < 6; ++c)
                #pragma unroll
                for (int j = 0; j < 8; ++j)
                    nxtB.b[c][j] = fldP[cbn + (int)koffR[c * 8 + j]];
        }
        f32x4 acc = {0.0f, 0.0f, 0.0f, 0.0f};
        #pragma unroll
        for (int c = 0; c < 6; ++c)
            acc = __builtin_amdgcn_mfma_f32_16x16x32_f16(af[c], curB.b[c], acc, 0, 0, 0);
        if (sc_ < 324) {
            #pragma unroll
            for (int r = 0; r < 4; ++r) {
                f16* pp = &outB[(4 * g + r) * 324 + sc_];
                if (p01c == 0) *pp = (f16)acc[r];
                else           *pp = (f16)fmaxf((float)*pp, acc[r]);
            }
        }
        curB = nxtB;
        p01c = p01n;
        sc_ = sn;
    }
    __syncthreads();

    for (int i = tid; i < 1296; i += 256) {
        const int oc = i & 15, sp = i >> 4, Y = sp / 9, Z = sp % 9;
        float mx = -1e30f;
        #pragma unroll
        for (int u = 0; u < 4; ++u) {
            const int dy = u >> 1, dz = u & 1;
            mx = fmaxf(mx, (float)outB[oc * 324 + (2 * Y + dy) * 18 + (2 * Z + dz)]);
        }
        const float v = mx + bs[oc];
        a1[((size_t)b * 729 + Xg * 81 + Y * 9 + Z) * 16 + oc] = v;
        atomicAdd(&s_sum[oc], v);
        atomicAdd(&s_ssq[oc], v * v);
    }
    __syncthreads();
    if (tid < 16) { atomicAdd(&stO[tid], s_sum[tid]); atomicAdd(&stO[16 + tid], s_ssq[tid]); }
}

// ---------- K2: bn1+leaky -> conv2 (16->32, pad0) + pool -> [32,3^3] + bn2 stats
__global__ __launch_bounds__(320) void k_conv2(const float* __restrict__ a1,
        const float* __restrict__ w, const float* __restrict__ bias,
        const float* __restrict__ bng, const float* __restrict__ bnb,
        const float* __restrict__ stI, float* __restrict__ a2,
        float* __restrict__ stO) {
    __shared__ float xin[16 * 729];
    __shared__ float ws2[6912];
    __shared__ float sc[16], sh[16];
    __shared__ float s_sum[16], s_ssq[16];
    const int bx = blockIdx.x, b = bx >> 1, half = bx & 1, tid = threadIdx.x;
    if (tid < 16) {
        const float cnt = 256.0f * 729.0f;
        float m = stI[tid] / cnt;
        float v = stI[16 + tid] / cnt - m * m;
        float s = bng[tid] * rsqrtf(fmaxf(v, 0.0f) + EPS);
        sc[tid] = s; sh[tid] = bnb[tid] - m * s;
        s_sum[tid] = 0.0f; s_ssq[tid] = 0.0f;
    }
    __syncthreads();
    const float* src = a1 + (size_t)b * 729 * 16;
    for (int i = tid; i < 16 * 729; i += 320) {
        const int spb = i >> 4, c = i & 15;
        xin[c * 729 + spb] = leaky(src[i] * sc[c] + sh[c]);
    }
    for (int i = tid; i < 6912; i += 320) ws2[i] = w[half * 6912 + i];
    __syncthreads();
    if (tid < 288) {
        const int oyi = tid & 1, oxi = (tid >> 1) & 1, rest = tid >> 2;
        const int Y = rest % 3, X = (rest / 3) % 3, c2 = rest / 9;
        const int ox = 2 * X + oxi, oy = 2 * Y + oyi;
        const int cl0 = 2 * c2, cl1 = cl0 + 1;
        float acc0[6], acc1[6];
        #pragma unroll
        for (int z = 0; z < 6; ++z) { acc0[z] = 0.0f; acc1[z] = 0.0f; }
        for (int ic = 0; ic < 16; ++ic) {
            #pragma unroll
            for (int dx = 0; dx < 3; ++dx) {
                const int ix = ox + dx;
                #pragma unroll
                for (int dy = 0; dy < 3; ++dy) {
                    const int iy = oy + dy;
                    const float* rp = &xin[ic * 729 + ix * 81 + iy * 9];
                    float row[9];
                    #pragma unroll
                    for (int z = 0; z < 9; ++z) row[z] = rp[z];
                    const int wb0 = (cl0 * 16 + ic) * 27 + dx * 9 + dy * 3;
                    const int wb1 = (cl1 * 16 + ic) * 27 + dx * 9 + dy * 3;
                    #pragma unroll
                    for (int dz = 0; dz < 3; ++dz) {
                        const float w0 = ws2[wb0 + dz];
                        const float w1v = ws2[wb1 + dz];
                        #pragma unroll
                        for (int z = 0; z < 6; ++z) {
                            acc0[z] += w0 * row[z + dz];
                            acc1[z] += w1v * row[z + dz];
                        }
                    }
                }
            }
        }
        float pl[2][3];
        #pragma unroll
        for (int Z = 0; Z < 3; ++Z) {
            float v0 = fmaxf(acc0[2 * Z], acc0[2 * Z + 1]);
            float v1 = fmaxf(acc1[2 * Z], acc1[2 * Z + 1]);
            v0 = fmaxf(v0, __shfl_xor(v0, 1)); v0 = fmaxf(v0, __shfl_xor(v0, 2));
            v1 = fmaxf(v1, __shfl_xor(v1, 1)); v1 = fmaxf(v1, __shfl_xor(v1, 2));
            pl[0][Z] = v0; pl[1][Z] = v1;
        }
        if ((tid & 3) == 0) {
            #pragma unroll
            for (int hh = 0; hh < 2; ++hh) {
                const int cl = cl0 + hh, c = half * 16 + cl;
                const float bb = bias[c];
                float s0 = 0.0f, q0 = 0.0f;
                #pragma unroll
                for (int Z = 0; Z < 3; ++Z) {
                    const float v = pl[hh][Z] + bb;
                    a2[((size_t)b * 32 + c) * 27 + X * 9 + Y * 3 + Z] = v;
                    s0 += v; q0 += v * v;
                }
                atomicAdd(&s_sum[cl], s0); atomicAdd(&s_ssq[cl], q0);
            }
        }
    }
    __syncthreads();
    if (tid < 16) {
        const int c = half * 16 + tid;
        atomicAdd(&stO[c], s_sum[tid]); atomicAdd(&stO[32 + c], s_ssq[tid]);
    }
}

// ---------- K3: bn2+leaky -> conv3 (32->64, pad1, 3^3) + pool -> [64] + bn3 stats
__global__ __launch_bounds__(256) void k_conv3(const float* __restrict__ a2,
        const float* __restrict__ w, const float* __restrict__ bias,
        const float* __restrict__ bng, const float* __restrict__ bnb,
        const float* __restrict__ stI, float* __restrict__ a3,
        float* __restrict__ stO) {
    __shared__ float x[864];
    __shared__ float pacc[256 * 8];
    __shared__ float sc[32], sh[32];
    const int b = blockIdx.x, tid = threadIdx.x;
    if (tid < 32) {
        const float cnt = 256.0f * 27.0f;
        float m = stI[tid] / cnt;
        float v = stI[32 + tid] / cnt - m * m;
        float s = bng[tid] * rsqrtf(fmaxf(v, 0.0f) + EPS);
        sc[tid] = s; sh[tid] = bnb[tid] - m * s;
    }
    __syncthreads();
    for (int i = tid; i < 864; i += 256) {
        int c = i / 27;
        x[i] = leaky(a2[(size_t)b * 864 + i] * sc[c] + sh[c]);
    }
    __syncthreads();
    const int c = tid & 63, q = tid >> 6;
    float acc[8];
    #pragma unroll
    for (int p = 0; p < 8; ++p) acc[p] = 0.0f;
    for (int ic = q * 8; ic < q * 8 + 8; ++ic) {
        const float* wr = w + ((size_t)c * 32 + ic) * 27;
        #pragma unroll
        for (int d = 0; d < 27; ++d) {
            const int dx = d / 9, dy = (d / 3) % 3, dz = d % 3;
            const float wv = wr[d];
            #pragma unroll
            for (int p = 0; p < 8; ++p) {
                const int px = p >> 2, py = (p >> 1) & 1, pz = p & 1;
                const int ix = px + dx - 1, iy = py + dy - 1, iz = pz + dz - 1;
                if (ix >= 0 && iy >= 0 && iz >= 0)
                    acc[p] += wv * x[ic * 27 + ix * 9 + iy * 3 + iz];
            }
        }
    }
    #pragma unroll
    for (int p = 0; p < 8; ++p) pacc[tid * 8 + p] = acc[p];
    __syncthreads();
    if (q == 0) {
        float m = -1e30f;
        #pragma unroll
        for (int p = 0; p < 8; ++p) {
            float v = pacc[c * 8 + p] + pacc[(64 + c) * 8 + p]
                    + pacc[(128 + c) * 8 + p] + pacc[(192 + c) * 8 + p];
            m = fmaxf(m, v);
        }
        float v = m + bias[c];
        a3[(size_t)b * 64 + c] = v;
        atomicAdd(&stO[c], v); atomicAdd(&stO[64 + c], v * v);
    }
}

// ---------- K4: bn3+leaky -> dense 64->128 (pre-bn4) + bn4 stats
__global__ __launch_bounds__(128) void k_dense1(const float* __restrict__ a3,
        const float* __restrict__ bng, const float* __restrict__ bnb,
        const float* __restrict__ stI,
        const float* __restrict__ w1, const float* __restrict__ b1,
        float* __restrict__ h1, float* __restrict__ stO) {
    __shared__ float x[64];
    const int b = blockIdx.x, tid = threadIdx.x;
    if (tid < 64) {
        float m = stI[tid] / 256.0f;
        float v = stI[64 + tid] / 256.0f - m * m;
        float s = bng[tid] * rsqrtf(fmaxf(v, 0.0f) + EPS);
        x[tid] = leaky(a3[(size_t)b * 64 + tid] * s + (bnb[tid] - m * s));
    }
    __syncthreads();
    const float* wr = w1 + tid * 64;
    float acc = b1[tid];
    #pragma unroll
    for (int i = 0; i < 64; ++i) acc += x[i] * wr[i];
    h1[(size_t)b * 128 + tid] = acc;
    atomicAdd(&stO[tid], acc); atomicAdd(&stO[128 + tid], acc * acc);
}

// ---------- K5: bn4+leaky -> 128->100 (+leaky) -> 100->20 -> out (f32)
__global__ __launch_bounds__(128) void k_dense2(const float* __restrict__ h1,
        const float* __restrict__ bng, const float* __restrict__ bnb,
        const float* __restrict__ stI,
        const float* __restrict__ w2, const float* __restrict__ bias2,
        const float* __restrict__ w3, const float* __restrict__ bias3,
        float* __restrict__ out) {
    __shared__ float x[128];
    __shared__ float y[100];
    const int b = blockIdx.x, tid = threadIdx.x;
    {
        float m = stI[tid] / 256.0f;
        float v = stI[128 + tid] / 256.0f - m * m;
        float s = bng[tid] * rsqrtf(fmaxf(v, 0.0f) + EPS);
        x[tid] = leaky(h1[(size_t)b * 128 + tid] * s + (bnb[tid] - m * s));
    }
    __syncthreads();
    if (tid < 100) {
        const float* wr = w2 + tid * 128;
        float acc = bias2[tid];
        #pragma unroll
        for (int i = 0; i < 128; ++i) acc += x[i] * wr[i];
        y[tid] = leaky(acc);
    }
    __syncthreads();
    if (tid < 20) {
        const float* wr = w3 + tid * 100;
        float acc = bias3[tid];
        #pragma unroll
        for (int i = 0; i < 100; ++i) acc += y[i] * wr[i];
        out[(size_t)b * 20 + tid] = acc;
    }
}

extern "C" void kernel_launch(void* const* d_in, const int* in_sizes, int n_in,
                              void* d_out, int out_size, void* d_ws, size_t ws_size,
                              hipStream_t stream) {
    (void)in_sizes; (void)n_in; (void)out_size; (void)ws_size;
    const float* pos  = (const float*)d_in[0];
    const float* c1w  = (const float*)d_in[1];
    const float* c1b  = (const float*)d_in[2];
    const float* bn1g = (const float*)d_in[3];
    const float* bn1b = (const float*)d_in[4];
    const float* c2w  = (const float*)d_in[5];
    const float* c2b  = (const float*)d_in[6];
    const float* bn2g = (const float*)d_in[7];
    const float* bn2b = (const float*)d_in[8];
    const float* c3w  = (const float*)d_in[9];
    const float* c3b  = (const float*)d_in[10];
    const float* bn3g = (const float*)d_in[11];
    const float* bn3b = (const float*)d_in[12];
    const float* d1w  = (const float*)d_in[13];
    const float* d1b  = (const float*)d_in[14];
    const float* bn4g = (const float*)d_in[15];
    const float* bn4b = (const float*)d_in[16];
    const float* d2w  = (const float*)d_in[17];
    const float* d2b  = (const float*)d_in[18];
    const float* d3w  = (const float*)d_in[19];
    const float* d3b  = (const float*)d_in[20];
    const int* types  = (const int*)d_in[22];   // d_in[21]=batch_ids implied by layout

    float* ws = (float*)d_ws;
    float* st = ws;                         // 480 f bn stats
    float* a1 = ws + 512;                   // 2,985,984 f  [b][729][16]
    u32* fields = (u32*)(a1 + 2985984);     // f16 pairs: 4,478,976 u32 (~30 MB)
    float* a2 = (float*)(fields + 4478976); // 221,184 f
    float* a3 = a2 + 221184;                // 16,384 f
    float* h1 = a3 + 16384;                 // 32,768 f

    k_splat <<<BATCH, 512, 0, stream>>>(pos, types, fields, st);
    k_conv1 <<<9 * BATCH, 256, 0, stream>>>(fields, c1w, c1b, a1, st);
    k_conv2 <<<2 * BATCH, 320, 0, stream>>>(a1, c2w, c2b, bn1g, bn1b, st, a2, st + 32);
    k_conv3 <<<BATCH, 256, 0, stream>>>(a2, c3w, c3b, bn2g, bn2b, st + 32, a3, st + 96);
    k_dense1<<<BATCH, 128, 0, stream>>>(a3, bn3g, bn3b, st + 96, d1w, d1b, h1, st + 224);
    k_dense2<<<BATCH, 128, 0, stream>>>(h1, bn4g, bn4b, st + 224, d2w, d2b, d3w, d3b,
                                        (float*)d_out);
}

// Round 18
// 218.108 us; speedup vs baseline: 1.0809x; 1.0809x over previous
//
#include <hip/hip_runtime.h>

// CavityModel forward: gaussian blur -> 3x(conv3d+maxpool+BN(batch stats)+leaky)
// -> dense 64->128 (+BN+leaky) -> 128->100 (+leaky) -> 100->20.
// R18: conv1 reverted to R15 (proven 99us; R15/16/17 showed datapath edits are
// null-or-spill). Tail access patterns fixed: dense weight rows staged to LDS
// coalesced (+1 pad, was lane-stride-256B uncoalesced), conv2 float4 staging.

#define G2 324
#define G3 5832
#define NT 6
#define BATCH 256
#define APE 100
#define EPS 1e-5f

typedef unsigned short u16;
typedef unsigned int u32;
typedef _Float16 f16;
typedef _Float16 h2 __attribute__((ext_vector_type(2)));
typedef _Float16 f16x8 __attribute__((ext_vector_type(8)));
typedef float f32x4 __attribute__((ext_vector_type(4)));

__device__ __forceinline__ float leaky(float x) { return x >= 0.0f ? x : 0.01f * x; }
__device__ __forceinline__ u32 pkh(float a, float b) {
    h2 v; v[0] = (f16)a; v[1] = (f16)b;
    return __builtin_bit_cast(u32, v);
}

// ---------- K1a: gaussian splat, separable outer product, NO atomics.
// block 0 zeroes the bn-stats buffer (runs strictly before all consumers).
__global__ __launch_bounds__(512) void k_splat(const float* __restrict__ pos,
        const int* __restrict__ types, u32* __restrict__ fields,
        float* __restrict__ stO) {
    __shared__ float ew[APE * 54];
    __shared__ float ssum[APE * 3];
    __shared__ int list[APE];
    __shared__ int base[NT + 1];
    __shared__ int cnt[NT], cur[NT];
    const int b = blockIdx.x, tid = threadIdx.x;

    if (b == 0 && tid < 480) stO[tid] = 0.0f;
    if (tid < NT) { cnt[tid] = 0; cur[tid] = 0; }
    __syncthreads();
    if (tid < APE) atomicAdd(&cnt[types[b * APE + tid]], 1);
    if (tid < 300) {
        const int la = tid / 3, ax = tid % 3;
        const float p = pos[(b * APE + la) * 3 + ax];
        float s = 0.0f;
        #pragma unroll
        for (int g = 0; g < 18; ++g) {
            const float d = (float)g - 8.5f - p;
            const float e = __expf(d * d * (-1.0f / 0.72f));
            ew[la * 54 + ax * 18 + g] = e;
            s += e;
        }
        ssum[tid] = s;
    }
    __syncthreads();
    if (tid == 0) {
        int s = 0;
        #pragma unroll
        for (int t = 0; t < NT; ++t) { base[t] = s; s += cnt[t]; }
        base[NT] = s;
    }
    if (tid < APE) {
        const float inv = 1.0f / (ssum[tid * 3] * ssum[tid * 3 + 1] * ssum[tid * 3 + 2]);
        #pragma unroll
        for (int g = 0; g < 18; ++g) ew[tid * 54 + g] *= inv;
    }
    __syncthreads();
    if (tid < APE) {
        const int t = types[b * APE + tid];
        const int j = atomicAdd(&cur[t], 1);
        list[base[t] + j] = tid;
    }
    __syncthreads();

    for (int it = tid; it < NT * 324; it += 512) {
        const int t = it / 324, r = it - t * 324;
        const int i = r / 18, j = r % 18;
        float acc[18];
        #pragma unroll
        for (int k = 0; k < 18; ++k) acc[k] = 0.0f;
        const int e1 = base[t + 1];
        for (int u = base[t]; u < e1; ++u) {
            const int a = list[u];
            const float exy = ew[a * 54 + i] * ew[a * 54 + 18 + j];
            const float* ez = &ew[a * 54 + 36];
            #pragma unroll
            for (int k = 0; k < 18; ++k) acc[k] += exy * ez[k];
        }
        u32* dst = &fields[((size_t)b * NT + t) * 2916 + (size_t)r * 9];
        #pragma unroll
        for (int q = 0; q < 9; ++q) dst[q] = pkh(acc[2 * q], acc[2 * q + 1]);
    }
}

// ---------- K1b: conv1 via MFMA implicit GEMM + 2x2x2 pool + bias + bn1 stats
// R15-PROVEN BODY (98.6us). Do not restructure: R15/R16/R17 were null/spill.
__global__ __launch_bounds__(256, 3) void k_conv1(const u32* __restrict__ fields,
        const float* __restrict__ w, const float* __restrict__ bias,
        float* __restrict__ a1, float* __restrict__ stO) {
    __shared__ f16 fldP[9600];     // 19200 B: [ic][pl][y][z] strides 1600/400/20/1
    __shared__ f16 outB[16 * 648]; // 20736 B: conv out [oc][s], s = oxl*324+oy*18+oz
    __shared__ u16 koffT[192];     // element offsets per k
    __shared__ float bs[16], s_sum[16], s_ssq[16];
    const int bx = blockIdx.x, b = bx / 9, Xg = bx % 9, tid = threadIdx.x;

    for (int i = tid; i < 4800; i += 256) ((u32*)fldP)[i] = 0u;
    if (tid < 192) {
        u16 off = 0;
        if (tid < 162) {
            const int ic = tid / 27, d = tid % 27;
            off = (u16)(ic * 1600 + (d / 9) * 400 + ((d / 3) % 3) * 20 + (d % 3));
        }
        koffT[tid] = off;
    }
    if (tid < 16) { bs[tid] = bias[tid]; s_sum[tid] = 0.0f; s_ssq[tid] = 0.0f; }

    const int lane = tid & 63, g = lane >> 4, m = lane & 15, wv = tid >> 6;
    f16x8 af[6];
    #pragma unroll
    for (int c = 0; c < 6; ++c)
        #pragma unroll
        for (int j = 0; j < 8; ++j) {
            const int k = 32 * c + 8 * g + j;
            af[c][j] = (k < 162) ? (f16)w[m * 162 + k] : (f16)0.0f;
        }
    __syncthreads();

    for (int i = tid; i < 3888; i += 256) {
        const int p = i % 9, r2 = i / 9, iy = r2 % 18, r3 = r2 / 18;
        const int pl = r3 & 3, ic = r3 >> 2;
        const int ix = 2 * Xg - 1 + pl;
        if (ix >= 0 && ix < 18) {
            const u32 v = fields[((size_t)(b * 6 + ic) * 324 + ix * 18 + iy) * 9 + p];
            const h2 hv = __builtin_bit_cast(h2, v);
            const int e = ic * 1600 + pl * 400 + (iy + 1) * 20 + (2 * p + 1);
            fldP[e] = hv[0];
            fldP[e + 1] = hv[1];
        }
    }
    __syncthreads();

    u16 koffR[48];
    #pragma unroll
    for (int c = 0; c < 6; ++c)
        #pragma unroll
        for (int j = 0; j < 8; ++j)
            koffR[c * 8 + j] = koffT[32 * c + 8 * g + j];

    for (int t = wv; t < 41; t += 4) {
        const int s = 16 * t + m;
        const int sv = (s < 648) ? s : 647;
        const int oxl = sv / 324, rem = sv % 324, oy = rem / 18, oz = rem % 18;
        const int cb = oxl * 400 + oy * 20 + oz;
        f32x4 acc = {0.0f, 0.0f, 0.0f, 0.0f};
        #pragma unroll
        for (int c = 0; c < 6; ++c) {
            f16x8 bf;
            #pragma unroll
            for (int j = 0; j < 8; ++j)
                bf[j] = fldP[cb + (int)koffR[c * 8 + j]];
            acc = __builtin_amdgcn_mfma_f32_16x16x32_f16(af[c], bf, acc, 0, 0, 0);
        }
        if (s < 648) {
            #pragma unroll
            for (int r = 0; r < 4; ++r)
                outB[(4 * g + r) * 648 + s] = (f16)acc[r];
        }
    }
    __syncthreads();

    for (int i = tid; i < 1296; i += 256) {
        const int oc = i & 15, sp = i >> 4, Y = sp / 9, Z = sp % 9;
        float mx = -1e30f;
        #pragma unroll
        for (int u = 0; u < 8; ++u) {
            const int ox = u >> 2, dy = (u >> 1) & 1, dz = u & 1;
            mx = fmaxf(mx, (float)outB[oc * 648 + ox * 324
                                       + (2 * Y + dy) * 18 + (2 * Z + dz)]);
        }
        const float v = mx + bs[oc];
        a1[((size_t)b * 729 + Xg * 81 + Y * 9 + Z) * 16 + oc] = v;
        atomicAdd(&s_sum[oc], v);
        atomicAdd(&s_ssq[oc], v * v);
    }
    __syncthreads();
    if (tid < 16) { atomicAdd(&stO[tid], s_sum[tid]); atomicAdd(&stO[16 + tid], s_ssq[tid]); }
}

// ---------- K2: bn1+leaky -> conv2 (16->32, pad0) + pool -> [32,3^3] + bn2 stats
// oc-split: block = (env, half); float4 staging for activations and weights.
__global__ __launch_bounds__(320) void k_conv2(const float* __restrict__ a1,
        const float* __restrict__ w, const float* __restrict__ bias,
        const float* __restrict__ bng, const float* __restrict__ bnb,
        const float* __restrict__ stI, float* __restrict__ a2,
        float* __restrict__ stO) {
    __shared__ float xin[16 * 729];     // 46656 B
    __shared__ float ws2[6912];         // half of weights: 27648 B
    __shared__ float sc[16], sh[16];
    __shared__ float s_sum[16], s_ssq[16];
    const int bx = blockIdx.x, b = bx >> 1, half = bx & 1, tid = threadIdx.x;
    if (tid < 16) {
        const float cnt = 256.0f * 729.0f;
        float m = stI[tid] / cnt;
        float v = stI[16 + tid] / cnt - m * m;
        float s = bng[tid] * rsqrtf(fmaxf(v, 0.0f) + EPS);
        sc[tid] = s; sh[tid] = bnb[tid] - m * s;
        s_sum[tid] = 0.0f; s_ssq[tid] = 0.0f;
    }
    __syncthreads();
    const float4* src4 = (const float4*)(a1 + (size_t)b * 729 * 16);
    for (int i = tid; i < 2916; i += 320) {          // 729*16/4
        const float4 v = src4[i];
        const int spb = i >> 2, c0 = (i & 3) * 4;
        xin[(c0 + 0) * 729 + spb] = leaky(v.x * sc[c0 + 0] + sh[c0 + 0]);
        xin[(c0 + 1) * 729 + spb] = leaky(v.y * sc[c0 + 1] + sh[c0 + 1]);
        xin[(c0 + 2) * 729 + spb] = leaky(v.z * sc[c0 + 2] + sh[c0 + 2]);
        xin[(c0 + 3) * 729 + spb] = leaky(v.w * sc[c0 + 3] + sh[c0 + 3]);
    }
    {
        const float4* w4 = (const float4*)(w + half * 6912);
        float4* d4 = (float4*)ws2;
        for (int i = tid; i < 1728; i += 320) d4[i] = w4[i];
    }
    __syncthreads();
    if (tid < 288) {
        const int oyi = tid & 1, oxi = (tid >> 1) & 1, rest = tid >> 2;
        const int Y = rest % 3, X = (rest / 3) % 3, c2 = rest / 9;   // c2 0..7
        const int ox = 2 * X + oxi, oy = 2 * Y + oyi;   // 0..5
        const int cl0 = 2 * c2, cl1 = cl0 + 1;
        float acc0[6], acc1[6];
        #pragma unroll
        for (int z = 0; z < 6; ++z) { acc0[z] = 0.0f; acc1[z] = 0.0f; }
        for (int ic = 0; ic < 16; ++ic) {
            #pragma unroll
            for (int dx = 0; dx < 3; ++dx) {
                const int ix = ox + dx;
                #pragma unroll
                for (int dy = 0; dy < 3; ++dy) {
                    const int iy = oy + dy;
                    const float* rp = &xin[ic * 729 + ix * 81 + iy * 9];
                    float row[9];
                    #pragma unroll
                    for (int z = 0; z < 9; ++z) row[z] = rp[z];
                    const int wb0 = (cl0 * 16 + ic) * 27 + dx * 9 + dy * 3;
                    const int wb1 = (cl1 * 16 + ic) * 27 + dx * 9 + dy * 3;
                    #pragma unroll
                    for (int dz = 0; dz < 3; ++dz) {
                        const float w0 = ws2[wb0 + dz];
                        const float w1v = ws2[wb1 + dz];
                        #pragma unroll
                        for (int z = 0; z < 6; ++z) {
                            acc0[z] += w0 * row[z + dz];
                            acc1[z] += w1v * row[z + dz];
                        }
                    }
                }
            }
        }
        float pl[2][3];
        #pragma unroll
        for (int Z = 0; Z < 3; ++Z) {
            float v0 = fmaxf(acc0[2 * Z], acc0[2 * Z + 1]);
            float v1 = fmaxf(acc1[2 * Z], acc1[2 * Z + 1]);
            v0 = fmaxf(v0, __shfl_xor(v0, 1)); v0 = fmaxf(v0, __shfl_xor(v0, 2));
            v1 = fmaxf(v1, __shfl_xor(v1, 1)); v1 = fmaxf(v1, __shfl_xor(v1, 2));
            pl[0][Z] = v0; pl[1][Z] = v1;
        }
        if ((tid & 3) == 0) {
            #pragma unroll
            for (int hh = 0; hh < 2; ++hh) {
                const int cl = cl0 + hh, c = half * 16 + cl;
                const float bb = bias[c];
                float s0 = 0.0f, q0 = 0.0f;
                #pragma unroll
                for (int Z = 0; Z < 3; ++Z) {
                    const float v = pl[hh][Z] + bb;
                    a2[((size_t)b * 32 + c) * 27 + X * 9 + Y * 3 + Z] = v;
                    s0 += v; q0 += v * v;
                }
                atomicAdd(&s_sum[cl], s0); atomicAdd(&s_ssq[cl], q0);
            }
        }
    }
    __syncthreads();
    if (tid < 16) {
        const int c = half * 16 + tid;
        atomicAdd(&stO[c], s_sum[tid]); atomicAdd(&stO[32 + c], s_ssq[tid]);
    }
}

// ---------- K3: bn2+leaky -> conv3 (32->64, pad1, 3^3) + pool -> [64] + bn3 stats
__global__ __launch_bounds__(256) void k_conv3(const float* __restrict__ a2,
        const float* __restrict__ w, const float* __restrict__ bias,
        const float* __restrict__ bng, const float* __restrict__ bnb,
        const float* __restrict__ stI, float* __restrict__ a3,
        float* __restrict__ stO) {
    __shared__ float x[864];
    __shared__ float pacc[256 * 8];
    __shared__ float sc[32], sh[32];
    const int b = blockIdx.x, tid = threadIdx.x;
    if (tid < 32) {
        const float cnt = 256.0f * 27.0f;
        float m = stI[tid] / cnt;
        float v = stI[32 + tid] / cnt - m * m;
        float s = bng[tid] * rsqrtf(fmaxf(v, 0.0f) + EPS);
        sc[tid] = s; sh[tid] = bnb[tid] - m * s;
    }
    __syncthreads();
    for (int i = tid; i < 864; i += 256) {
        int c = i / 27;
        x[i] = leaky(a2[(size_t)b * 864 + i] * sc[c] + sh[c]);
    }
    __syncthreads();
    const int c = tid & 63, q = tid >> 6;
    float acc[8];
    #pragma unroll
    for (int p = 0; p < 8; ++p) acc[p] = 0.0f;
    for (int ic = q * 8; ic < q * 8 + 8; ++ic) {
        const float* wr = w + ((size_t)c * 32 + ic) * 27;
        #pragma unroll
        for (int d = 0; d < 27; ++d) {
            const int dx = d / 9, dy = (d / 3) % 3, dz = d % 3;
            const float wv = wr[d];
            #pragma unroll
            for (int p = 0; p < 8; ++p) {
                const int px = p >> 2, py = (p >> 1) & 1, pz = p & 1;
                const int ix = px + dx - 1, iy = py + dy - 1, iz = pz + dz - 1;
                if (ix >= 0 && iy >= 0 && iz >= 0)
                    acc[p] += wv * x[ic * 27 + ix * 9 + iy * 3 + iz];
            }
        }
    }
    #pragma unroll
    for (int p = 0; p < 8; ++p) pacc[tid * 8 + p] = acc[p];
    __syncthreads();
    if (q == 0) {
        float m = -1e30f;
        #pragma unroll
        for (int p = 0; p < 8; ++p) {
            float v = pacc[c * 8 + p] + pacc[(64 + c) * 8 + p]
                    + pacc[(128 + c) * 8 + p] + pacc[(192 + c) * 8 + p];
            m = fmaxf(m, v);
        }
        float v = m + bias[c];
        a3[(size_t)b * 64 + c] = v;
        atomicAdd(&stO[c], v); atomicAdd(&stO[64 + c], v * v);
    }
}

// ---------- K4: bn3+leaky -> dense 64->128 (pre-bn4) + bn4 stats
// w1 staged to LDS coalesced (row pad 65 kills the stride-64 bank conflict).
__global__ __launch_bounds__(128) void k_dense1(const float* __restrict__ a3,
        const float* __restrict__ bng, const float* __restrict__ bnb,
        const float* __restrict__ stI,
        const float* __restrict__ w1, const float* __restrict__ b1,
        float* __restrict__ h1, float* __restrict__ stO) {
    __shared__ float x[64];
    __shared__ float wl[128 * 65];   // 33280 B
    const int b = blockIdx.x, tid = threadIdx.x;
    if (tid < 64) {
        float m = stI[tid] / 256.0f;
        float v = stI[64 + tid] / 256.0f - m * m;
        float s = bng[tid] * rsqrtf(fmaxf(v, 0.0f) + EPS);
        x[tid] = leaky(a3[(size_t)b * 64 + tid] * s + (bnb[tid] - m * s));
    }
    {
        const float4* w4 = (const float4*)w1;
        for (int i = tid; i < 2048; i += 128) {       // 128*64/4
            const float4 v = w4[i];
            const int row = i >> 4, col = (i & 15) * 4;
            wl[row * 65 + col + 0] = v.x;
            wl[row * 65 + col + 1] = v.y;
            wl[row * 65 + col + 2] = v.z;
            wl[row * 65 + col + 3] = v.w;
        }
    }
    __syncthreads();
    const float* wr = &wl[tid * 65];
    float acc = b1[tid];
    #pragma unroll
    for (int i = 0; i < 64; ++i) acc += x[i] * wr[i];
    h1[(size_t)b * 128 + tid] = acc;
    atomicAdd(&stO[tid], acc); atomicAdd(&stO[128 + tid], acc * acc);
}

// ---------- K5: bn4+leaky -> 128->100 (+leaky) -> 100->20 -> out (f32)
// w2/w3 staged to LDS coalesced (+1 row pad).
__global__ __launch_bounds__(128) void k_dense2(const float* __restrict__ h1,
        const float* __restrict__ bng, const float* __restrict__ bnb,
        const float* __restrict__ stI,
        const float* __restrict__ w2, const float* __restrict__ bias2,
        const float* __restrict__ w3, const float* __restrict__ bias3,
        float* __restrict__ out) {
    __shared__ float x[128];
    __shared__ float y[100];
    __shared__ float w2l[100 * 129];   // 51600 B
    __shared__ float w3l[20 * 101];    // 8080 B
    const int b = blockIdx.x, tid = threadIdx.x;
    {
        float m = stI[tid] / 256.0f;
        float v = stI[128 + tid] / 256.0f - m * m;
        float s = bng[tid] * rsqrtf(fmaxf(v, 0.0f) + EPS);
        x[tid] = leaky(h1[(size_t)b * 128 + tid] * s + (bnb[tid] - m * s));
    }
    {
        const float4* w4 = (const float4*)w2;
        for (int i = tid; i < 3200; i += 128) {       // 100*128/4
            const float4 v = w4[i];
            const int row = i >> 5, col = (i & 31) * 4;
            w2l[row * 129 + col + 0] = v.x;
            w2l[row * 129 + col + 1] = v.y;
            w2l[row * 129 + col + 2] = v.z;
            w2l[row * 129 + col + 3] = v.w;
        }
        for (int i = tid; i < 2000; i += 128) {       // 20*100
            const int row = i / 100, col = i % 100;
            w3l[row * 101 + col] = w3[i];
        }
    }
    __syncthreads();
    if (tid < 100) {
        const float* wr = &w2l[tid * 129];
        float acc = bias2[tid];
        #pragma unroll
        for (int i = 0; i < 128; ++i) acc += x[i] * wr[i];
        y[tid] = leaky(acc);
    }
    __syncthreads();
    if (tid < 20) {
        const float* wr = &w3l[tid * 101];
        float acc = bias3[tid];
        #pragma unroll
        for (int i = 0; i < 100; ++i) acc += y[i] * wr[i];
        out[(size_t)b * 20 + tid] = acc;
    }
}

extern "C" void kernel_launch(void* const* d_in, const int* in_sizes, int n_in,
                              void* d_out, int out_size, void* d_ws, size_t ws_size,
                              hipStream_t stream) {
    (void)in_sizes; (void)n_in; (void)out_size; (void)ws_size;
    const float* pos  = (const float*)d_in[0];
    const float* c1w  = (const float*)d_in[1];
    const float* c1b  = (const float*)d_in[2];
    const float* bn1g = (const float*)d_in[3];
    const float* bn1b = (const float*)d_in[4];
    const float* c2w  = (const float*)d_in[5];
    const float* c2b  = (const float*)d_in[6];
    const float* bn2g = (const float*)d_in[7];
    const float* bn2b = (const float*)d_in[8];
    const float* c3w  = (const float*)d_in[9];
    const float* c3b  = (const float*)d_in[10];
    const float* bn3g = (const float*)d_in[11];
    const float* bn3b = (const float*)d_in[12];
    const float* d1w  = (const float*)d_in[13];
    const float* d1b  = (const float*)d_in[14];
    const float* bn4g = (const float*)d_in[15];
    const float* bn4b = (const float*)d_in[16];
    const float* d2w  = (const float*)d_in[17];
    const float* d2b  = (const float*)d_in[18];
    const float* d3w  = (const float*)d_in[19];
    const float* d3b  = (const float*)d_in[20];
    const int* types  = (const int*)d_in[22];   // d_in[21]=batch_ids implied by layout

    float* ws = (float*)d_ws;
    float* st = ws;                         // 480 f bn stats
    float* a1 = ws + 512;                   // 2,985,984 f  [b][729][16]
    u32* fields = (u32*)(a1 + 2985984);     // f16 pairs: 4,478,976 u32 (~30 MB)
    float* a2 = (float*)(fields + 4478976); // 221,184 f
    float* a3 = a2 + 221184;                // 16,384 f
    float* h1 = a3 + 16384;                 // 32,768 f

    k_splat <<<BATCH, 512, 0, stream>>>(pos, types, fields, st);
    k_conv1 <<<9 * BATCH, 256, 0, stream>>>(fields, c1w, c1b, a1, st);
    k_conv2 <<<2 * BATCH, 320, 0, stream>>>(a1, c2w, c2b, bn1g, bn1b, st, a2, st + 32);
    k_conv3 <<<BATCH, 256, 0, stream>>>(a2, c3w, c3b, bn2g, bn2b, st + 32, a3, st + 96);
    k_dense1<<<BATCH, 128, 0, stream>>>(a3, bn3g, bn3b, st + 96, d1w, d1b, h1, st + 224);
    k_dense2<<<BATCH, 128, 0, stream>>>(h1, bn4g, bn4b, st + 224, d2w, d2b, d3w, d3b,
                                        (float*)d_out);
}

// Round 19
// 214.555 us; speedup vs baseline: 1.0988x; 1.0166x over previous
//
#include <hip/hip_runtime.h>

// CavityModel forward: gaussian blur -> 3x(conv3d+maxpool+BN(batch stats)+leaky)
// -> dense 64->128 (+BN+leaky) -> 128->100 (+leaky) -> 100->20.
// R19: verbatim revert to the R15 configuration (session best: 214.1 us).
// Ledger: conv1 datapath edits null/null/spill (R15/16/17); persistent tail
// fusion -28us (R12); tail LDS weight staging -4us (R18). Banking the optimum:
// - splat: separable outer-product, no atomics, f16 fields, stats-memset folded
// - conv1: MFMA implicit GEMM (16x16x32_f16), 99us, VGPR 52, no scratch
// - conv2: oc-split 2 blocks/env; conv3/dense: per-env small kernels.

#define G2 324
#define G3 5832
#define NT 6
#define BATCH 256
#define APE 100
#define EPS 1e-5f

typedef unsigned short u16;
typedef unsigned int u32;
typedef _Float16 f16;
typedef _Float16 h2 __attribute__((ext_vector_type(2)));
typedef _Float16 f16x8 __attribute__((ext_vector_type(8)));
typedef float f32x4 __attribute__((ext_vector_type(4)));

__device__ __forceinline__ float leaky(float x) { return x >= 0.0f ? x : 0.01f * x; }
__device__ __forceinline__ u32 pkh(float a, float b) {
    h2 v; v[0] = (f16)a; v[1] = (f16)b;
    return __builtin_bit_cast(u32, v);
}

// ---------- K1a: gaussian splat, separable outer product, NO atomics.
// block 0 zeroes the bn-stats buffer (runs strictly before all consumers).
__global__ __launch_bounds__(512) void k_splat(const float* __restrict__ pos,
        const int* __restrict__ types, u32* __restrict__ fields,
        float* __restrict__ stO) {
    __shared__ float ew[APE * 54];
    __shared__ float ssum[APE * 3];
    __shared__ int list[APE];
    __shared__ int base[NT + 1];
    __shared__ int cnt[NT], cur[NT];
    const int b = blockIdx.x, tid = threadIdx.x;

    if (b == 0 && tid < 480) stO[tid] = 0.0f;
    if (tid < NT) { cnt[tid] = 0; cur[tid] = 0; }
    __syncthreads();
    if (tid < APE) atomicAdd(&cnt[types[b * APE + tid]], 1);
    if (tid < 300) {
        const int la = tid / 3, ax = tid % 3;
        const float p = pos[(b * APE + la) * 3 + ax];
        float s = 0.0f;
        #pragma unroll
        for (int g = 0; g < 18; ++g) {
            const float d = (float)g - 8.5f - p;
            const float e = __expf(d * d * (-1.0f / 0.72f));
            ew[la * 54 + ax * 18 + g] = e;
            s += e;
        }
        ssum[tid] = s;
    }
    __syncthreads();
    if (tid == 0) {
        int s = 0;
        #pragma unroll
        for (int t = 0; t < NT; ++t) { base[t] = s; s += cnt[t]; }
        base[NT] = s;
    }
    if (tid < APE) {
        const float inv = 1.0f / (ssum[tid * 3] * ssum[tid * 3 + 1] * ssum[tid * 3 + 2]);
        #pragma unroll
        for (int g = 0; g < 18; ++g) ew[tid * 54 + g] *= inv;
    }
    __syncthreads();
    if (tid < APE) {
        const int t = types[b * APE + tid];
        const int j = atomicAdd(&cur[t], 1);
        list[base[t] + j] = tid;
    }
    __syncthreads();

    for (int it = tid; it < NT * 324; it += 512) {
        const int t = it / 324, r = it - t * 324;
        const int i = r / 18, j = r % 18;
        float acc[18];
        #pragma unroll
        for (int k = 0; k < 18; ++k) acc[k] = 0.0f;
        const int e1 = base[t + 1];
        for (int u = base[t]; u < e1; ++u) {
            const int a = list[u];
            const float exy = ew[a * 54 + i] * ew[a * 54 + 18 + j];
            const float* ez = &ew[a * 54 + 36];
            #pragma unroll
            for (int k = 0; k < 18; ++k) acc[k] += exy * ez[k];
        }
        u32* dst = &fields[((size_t)b * NT + t) * 2916 + (size_t)r * 9];
        #pragma unroll
        for (int q = 0; q < 9; ++q) dst[q] = pkh(acc[2 * q], acc[2 * q + 1]);
    }
}

// ---------- K1b: conv1 via MFMA implicit GEMM + 2x2x2 pool + bias + bn1 stats
// PROVEN BODY (98.6-99us). Do not restructure: R15/R16/R17 were null/spill.
__global__ __launch_bounds__(256, 3) void k_conv1(const u32* __restrict__ fields,
        const float* __restrict__ w, const float* __restrict__ bias,
        float* __restrict__ a1, float* __restrict__ stO) {
    __shared__ f16 fldP[9600];     // 19200 B: [ic][pl][y][z] strides 1600/400/20/1
    __shared__ f16 outB[16 * 648]; // 20736 B: conv out [oc][s], s = oxl*324+oy*18+oz
    __shared__ u16 koffT[192];     // element offsets per k
    __shared__ float bs[16], s_sum[16], s_ssq[16];
    const int bx = blockIdx.x, b = bx / 9, Xg = bx % 9, tid = threadIdx.x;

    for (int i = tid; i < 4800; i += 256) ((u32*)fldP)[i] = 0u;
    if (tid < 192) {
        u16 off = 0;
        if (tid < 162) {
            const int ic = tid / 27, d = tid % 27;
            off = (u16)(ic * 1600 + (d / 9) * 400 + ((d / 3) % 3) * 20 + (d % 3));
        }
        koffT[tid] = off;
    }
    if (tid < 16) { bs[tid] = bias[tid]; s_sum[tid] = 0.0f; s_ssq[tid] = 0.0f; }

    // A fragments: lane m = lane&15 (oc), k = 32c + 8g + j (g = lane>>4)
    const int lane = tid & 63, g = lane >> 4, m = lane & 15, wv = tid >> 6;
    f16x8 af[6];
    #pragma unroll
    for (int c = 0; c < 6; ++c)
        #pragma unroll
        for (int j = 0; j < 8; ++j) {
            const int k = 32 * c + 8 * g + j;
            af[c][j] = (k < 162) ? (f16)w[m * 162 + k] : (f16)0.0f;
        }
    __syncthreads();

    // stage interior: planes ix = 2Xg-1 .. 2Xg+2 (pads stay zero)
    for (int i = tid; i < 3888; i += 256) {
        const int p = i % 9, r2 = i / 9, iy = r2 % 18, r3 = r2 / 18;
        const int pl = r3 & 3, ic = r3 >> 2;
        const int ix = 2 * Xg - 1 + pl;
        if (ix >= 0 && ix < 18) {
            const u32 v = fields[((size_t)(b * 6 + ic) * 324 + ix * 18 + iy) * 9 + p];
            const h2 hv = __builtin_bit_cast(h2, v);
            const int e = ic * 1600 + pl * 400 + (iy + 1) * 20 + (2 * p + 1);
            fldP[e] = hv[0];
            fldP[e + 1] = hv[1];
        }
    }
    __syncthreads();

    // hoist this thread's 48 koff entries into registers (compile-time indexed)
    u16 koffR[48];
    #pragma unroll
    for (int c = 0; c < 6; ++c)
        #pragma unroll
        for (int j = 0; j < 8; ++j)
            koffR[c * 8 + j] = koffT[32 * c + 8 * g + j];

    // MFMA over 41 spatial tiles of 16 (648 positions, last tile ragged)
    for (int t = wv; t < 41; t += 4) {
        const int s = 16 * t + m;
        const int sv = (s < 648) ? s : 647;
        const int oxl = sv / 324, rem = sv % 324, oy = rem / 18, oz = rem % 18;
        // stage writes input (iy,iz) at padded index (iy+1,iz+1); tap needs
        // array index oy+dy (iy=oy+dy-1), koff contributes dy*20+dz -> base oy,oz.
        const int cb = oxl * 400 + oy * 20 + oz;
        f32x4 acc = {0.0f, 0.0f, 0.0f, 0.0f};
        #pragma unroll
        for (int c = 0; c < 6; ++c) {
            f16x8 bf;
            #pragma unroll
            for (int j = 0; j < 8; ++j)
                bf[j] = fldP[cb + (int)koffR[c * 8 + j]];
            acc = __builtin_amdgcn_mfma_f32_16x16x32_f16(af[c], bf, acc, 0, 0, 0);
        }
        if (s < 648) {
            #pragma unroll
            for (int r = 0; r < 4; ++r)
                outB[(4 * g + r) * 648 + s] = (f16)acc[r];
        }
    }
    __syncthreads();

    // 2x2x2 pool + bias -> a1 [b][spatial 729][ch 16] + bn1 stats
    for (int i = tid; i < 1296; i += 256) {
        const int oc = i & 15, sp = i >> 4, Y = sp / 9, Z = sp % 9;
        float mx = -1e30f;
        #pragma unroll
        for (int u = 0; u < 8; ++u) {
            const int ox = u >> 2, dy = (u >> 1) & 1, dz = u & 1;
            mx = fmaxf(mx, (float)outB[oc * 648 + ox * 324
                                       + (2 * Y + dy) * 18 + (2 * Z + dz)]);
        }
        const float v = mx + bs[oc];
        a1[((size_t)b * 729 + Xg * 81 + Y * 9 + Z) * 16 + oc] = v;
        atomicAdd(&s_sum[oc], v);
        atomicAdd(&s_ssq[oc], v * v);
    }
    __syncthreads();
    if (tid < 16) { atomicAdd(&stO[tid], s_sum[tid]); atomicAdd(&stO[16 + tid], s_ssq[tid]); }
}

// ---------- K2: bn1+leaky -> conv2 (16->32, pad0) + pool -> [32,3^3] + bn2 stats
// oc-split: block = (env, half); grid 2*BATCH (same-env adjacent); 320 threads.
__global__ __launch_bounds__(320) void k_conv2(const float* __restrict__ a1,
        const float* __restrict__ w, const float* __restrict__ bias,
        const float* __restrict__ bng, const float* __restrict__ bnb,
        const float* __restrict__ stI, float* __restrict__ a2,
        float* __restrict__ stO) {
    __shared__ float xin[16 * 729];     // 46656 B
    __shared__ float ws2[6912];         // half of weights: 27648 B
    __shared__ float sc[16], sh[16];
    __shared__ float s_sum[16], s_ssq[16];
    const int bx = blockIdx.x, b = bx >> 1, half = bx & 1, tid = threadIdx.x;
    if (tid < 16) {
        const float cnt = 256.0f * 729.0f;
        float m = stI[tid] / cnt;
        float v = stI[16 + tid] / cnt - m * m;
        float s = bng[tid] * rsqrtf(fmaxf(v, 0.0f) + EPS);
        sc[tid] = s; sh[tid] = bnb[tid] - m * s;
        s_sum[tid] = 0.0f; s_ssq[tid] = 0.0f;
    }
    __syncthreads();
    const float* src = a1 + (size_t)b * 729 * 16;
    for (int i = tid; i < 16 * 729; i += 320) {
        const int spb = i >> 4, c = i & 15;
        xin[c * 729 + spb] = leaky(src[i] * sc[c] + sh[c]);
    }
    for (int i = tid; i < 6912; i += 320) ws2[i] = w[half * 6912 + i];
    __syncthreads();
    if (tid < 288) {
        const int oyi = tid & 1, oxi = (tid >> 1) & 1, rest = tid >> 2;
        const int Y = rest % 3, X = (rest / 3) % 3, c2 = rest / 9;   // c2 0..7
        const int ox = 2 * X + oxi, oy = 2 * Y + oyi;   // 0..5
        const int cl0 = 2 * c2, cl1 = cl0 + 1;
        float acc0[6], acc1[6];
        #pragma unroll
        for (int z = 0; z < 6; ++z) { acc0[z] = 0.0f; acc1[z] = 0.0f; }
        for (int ic = 0; ic < 16; ++ic) {
            #pragma unroll
            for (int dx = 0; dx < 3; ++dx) {
                const int ix = ox + dx;
                #pragma unroll
                for (int dy = 0; dy < 3; ++dy) {
                    const int iy = oy + dy;
                    const float* rp = &xin[ic * 729 + ix * 81 + iy * 9];
                    float row[9];
                    #pragma unroll
                    for (int z = 0; z < 9; ++z) row[z] = rp[z];
                    const int wb0 = (cl0 * 16 + ic) * 27 + dx * 9 + dy * 3;
                    const int wb1 = (cl1 * 16 + ic) * 27 + dx * 9 + dy * 3;
                    #pragma unroll
                    for (int dz = 0; dz < 3; ++dz) {
                        const float w0 = ws2[wb0 + dz];
                        const float w1v = ws2[wb1 + dz];
                        #pragma unroll
                        for (int z = 0; z < 6; ++z) {
                            acc0[z] += w0 * row[z + dz];
                            acc1[z] += w1v * row[z + dz];
                        }
                    }
                }
            }
        }
        float pl[2][3];
        #pragma unroll
        for (int Z = 0; Z < 3; ++Z) {
            float v0 = fmaxf(acc0[2 * Z], acc0[2 * Z + 1]);
            float v1 = fmaxf(acc1[2 * Z], acc1[2 * Z + 1]);
            v0 = fmaxf(v0, __shfl_xor(v0, 1)); v0 = fmaxf(v0, __shfl_xor(v0, 2));
            v1 = fmaxf(v1, __shfl_xor(v1, 1)); v1 = fmaxf(v1, __shfl_xor(v1, 2));
            pl[0][Z] = v0; pl[1][Z] = v1;
        }
        if ((tid & 3) == 0) {
            #pragma unroll
            for (int hh = 0; hh < 2; ++hh) {
                const int cl = cl0 + hh, c = half * 16 + cl;
                const float bb = bias[c];
                float s0 = 0.0f, q0 = 0.0f;
                #pragma unroll
                for (int Z = 0; Z < 3; ++Z) {
                    const float v = pl[hh][Z] + bb;
                    a2[((size_t)b * 32 + c) * 27 + X * 9 + Y * 3 + Z] = v;
                    s0 += v; q0 += v * v;
                }
                atomicAdd(&s_sum[cl], s0); atomicAdd(&s_ssq[cl], q0);
            }
        }
    }
    __syncthreads();
    if (tid < 16) {
        const int c = half * 16 + tid;
        atomicAdd(&stO[c], s_sum[tid]); atomicAdd(&stO[32 + c], s_ssq[tid]);
    }
}

// ---------- K3: bn2+leaky -> conv3 (32->64, pad1, 3^3) + pool -> [64] + bn3 stats
__global__ __launch_bounds__(256) void k_conv3(const float* __restrict__ a2,
        const float* __restrict__ w, const float* __restrict__ bias,
        const float* __restrict__ bng, const float* __restrict__ bnb,
        const float* __restrict__ stI, float* __restrict__ a3,
        float* __restrict__ stO) {
    __shared__ float x[864];
    __shared__ float pacc[256 * 8];
    __shared__ float sc[32], sh[32];
    const int b = blockIdx.x, tid = threadIdx.x;
    if (tid < 32) {
        const float cnt = 256.0f * 27.0f;
        float m = stI[tid] / cnt;
        float v = stI[32 + tid] / cnt - m * m;
        float s = bng[tid] * rsqrtf(fmaxf(v, 0.0f) + EPS);
        sc[tid] = s; sh[tid] = bnb[tid] - m * s;
    }
    __syncthreads();
    for (int i = tid; i < 864; i += 256) {
        int c = i / 27;
        x[i] = leaky(a2[(size_t)b * 864 + i] * sc[c] + sh[c]);
    }
    __syncthreads();
    const int c = tid & 63, q = tid >> 6;
    float acc[8];
    #pragma unroll
    for (int p = 0; p < 8; ++p) acc[p] = 0.0f;
    for (int ic = q * 8; ic < q * 8 + 8; ++ic) {
        const float* wr = w + ((size_t)c * 32 + ic) * 27;
        #pragma unroll
        for (int d = 0; d < 27; ++d) {
            const int dx = d / 9, dy = (d / 3) % 3, dz = d % 3;
            const float wv = wr[d];
            #pragma unroll
            for (int p = 0; p < 8; ++p) {
                const int px = p >> 2, py = (p >> 1) & 1, pz = p & 1;
                const int ix = px + dx - 1, iy = py + dy - 1, iz = pz + dz - 1;
                if (ix >= 0 && iy >= 0 && iz >= 0)
                    acc[p] += wv * x[ic * 27 + ix * 9 + iy * 3 + iz];
            }
        }
    }
    #pragma unroll
    for (int p = 0; p < 8; ++p) pacc[tid * 8 + p] = acc[p];
    __syncthreads();
    if (q == 0) {
        float m = -1e30f;
        #pragma unroll
        for (int p = 0; p < 8; ++p) {
            float v = pacc[c * 8 + p] + pacc[(64 + c) * 8 + p]
                    + pacc[(128 + c) * 8 + p] + pacc[(192 + c) * 8 + p];
            m = fmaxf(m, v);
        }
        float v = m + bias[c];
        a3[(size_t)b * 64 + c] = v;
        atomicAdd(&stO[c], v); atomicAdd(&stO[64 + c], v * v);
    }
}

// ---------- K4: bn3+leaky -> dense 64->128 (pre-bn4) + bn4 stats
__global__ __launch_bounds__(128) void k_dense1(const float* __restrict__ a3,
        const float* __restrict__ bng, const float* __restrict__ bnb,
        const float* __restrict__ stI,
        const float* __restrict__ w1, const float* __restrict__ b1,
        float* __restrict__ h1, float* __restrict__ stO) {
    __shared__ float x[64];
    const int b = blockIdx.x, tid = threadIdx.x;
    if (tid < 64) {
        float m = stI[tid] / 256.0f;
        float v = stI[64 + tid] / 256.0f - m * m;
        float s = bng[tid] * rsqrtf(fmaxf(v, 0.0f) + EPS);
        x[tid] = leaky(a3[(size_t)b * 64 + tid] * s + (bnb[tid] - m * s));
    }
    __syncthreads();
    const float* wr = w1 + tid * 64;
    float acc = b1[tid];
    #pragma unroll
    for (int i = 0; i < 64; ++i) acc += x[i] * wr[i];
    h1[(size_t)b * 128 + tid] = acc;
    atomicAdd(&stO[tid], acc); atomicAdd(&stO[128 + tid], acc * acc);
}

// ---------- K5: bn4+leaky -> 128->100 (+leaky) -> 100->20 -> out (f32)
__global__ __launch_bounds__(128) void k_dense2(const float* __restrict__ h1,
        const float* __restrict__ bng, const float* __restrict__ bnb,
        const float* __restrict__ stI,
        const float* __restrict__ w2, const float* __restrict__ bias2,
        const float* __restrict__ w3, const float* __restrict__ bias3,
        float* __restrict__ out) {
    __shared__ float x[128];
    __shared__ float y[100];
    const int b = blockIdx.x, tid = threadIdx.x;
    {
        float m = stI[tid] / 256.0f;
        float v = stI[128 + tid] / 256.0f - m * m;
        float s = bng[tid] * rsqrtf(fmaxf(v, 0.0f) + EPS);
        x[tid] = leaky(h1[(size_t)b * 128 + tid] * s + (bnb[tid] - m * s));
    }
    __syncthreads();
    if (tid < 100) {
        const float* wr = w2 + tid * 128;
        float acc = bias2[tid];
        #pragma unroll
        for (int i = 0; i < 128; ++i) acc += x[i] * wr[i];
        y[tid] = leaky(acc);
    }
    __syncthreads();
    if (tid < 20) {
        const float* wr = w3 + tid * 100;
        float acc = bias3[tid];
        #pragma unroll
        for (int i = 0; i < 100; ++i) acc += y[i] * wr[i];
        out[(size_t)b * 20 + tid] = acc;
    }
}

extern "C" void kernel_launch(void* const* d_in, const int* in_sizes, int n_in,
                              void* d_out, int out_size, void* d_ws, size_t ws_size,
                              hipStream_t stream) {
    (void)in_sizes; (void)n_in; (void)out_size; (void)ws_size;
    const float* pos  = (const float*)d_in[0];
    const float* c1w  = (const float*)d_in[1];
    const float* c1b  = (const float*)d_in[2];
    const float* bn1g = (const float*)d_in[3];
    const float* bn1b = (const float*)d_in[4];
    const float* c2w  = (const float*)d_in[5];
    const float* c2b  = (const float*)d_in[6];
    const float* bn2g = (const float*)d_in[7];
    const float* bn2b = (const float*)d_in[8];
    const float* c3w  = (const float*)d_in[9];
    const float* c3b  = (const float*)d_in[10];
    const float* bn3g = (const float*)d_in[11];
    const float* bn3b = (const float*)d_in[12];
    const float* d1w  = (const float*)d_in[13];
    const float* d1b  = (const float*)d_in[14];
    const float* bn4g = (const float*)d_in[15];
    const float* bn4b = (const float*)d_in[16];
    const float* d2w  = (const float*)d_in[17];
    const float* d2b  = (const float*)d_in[18];
    const float* d3w  = (const float*)d_in[19];
    const float* d3b  = (const float*)d_in[20];
    const int* types  = (const int*)d_in[22];   // d_in[21]=batch_ids implied by layout

    float* ws = (float*)d_ws;
    float* st = ws;                         // 480 f bn stats
    float* a1 = ws + 512;                   // 2,985,984 f  [b][729][16]
    u32* fields = (u32*)(a1 + 2985984);     // f16 pairs: 4,478,976 u32 (~30 MB)
    float* a2 = (float*)(fields + 4478976); // 221,184 f
    float* a3 = a2 + 221184;                // 16,384 f
    float* h1 = a3 + 16384;                 // 32,768 f

    k_splat <<<BATCH, 512, 0, stream>>>(pos, types, fields, st);
    k_conv1 <<<9 * BATCH, 256, 0, stream>>>(fields, c1w, c1b, a1, st);
    k_conv2 <<<2 * BATCH, 320, 0, stream>>>(a1, c2w, c2b, bn1g, bn1b, st, a2, st + 32);
    k_conv3 <<<BATCH, 256, 0, stream>>>(a2, c3w, c3b, bn2g, bn2b, st + 32, a3, st + 96);
    k_dense1<<<BATCH, 128, 0, stream>>>(a3, bn3g, bn3b, st + 96, d1w, d1b, h1, st + 224);
    k_dense2<<<BATCH, 128, 0, stream>>>(h1, bn4g, bn4b, st + 224, d2w, d2b, d3w, d3b,
                                        (float*)d_out);
}